// Round 9
// baseline (274.759 us; speedup 1.0000x reference)
//
#include <hip/hip_runtime.h>
#include <math.h>

// Problem constants (B, C, H, W) = (32, 10, 192, 320), fp32.
constexpr int B_   = 32, C_ = 10, H_ = 192, W_ = 320;
constexpr int HW_  = H_ * W_;        // 61440 (divisible by 4)
constexpr int CHW_ = C_ * HW_;       // 614400
constexpr int NPTS = B_ * HW_;       // 1966080 spatial points
constexpr int NV4  = NPTS / 4;       // 491520 float4 points
constexpr int NBLK = NV4 / 256;      // 1920 blocks, exact cover

// Partial-sum slots, ws[slot * NBLK + blk], final weights folded in:
// 0: nv  1: num_pos
// 2: sum pos*(g0-r0)^2*log(safe+EPS)            (pos_term = -this)
// 3: sum neg*r0^2*log(1+EPS-safe)*(1-g0)^4      (neg_term = -this)
// 4: P  = 0.5*s_pos + 0.5*s_const + 0.1*s_h
// 5: V1 = 0.05*s_len1 + 0.5*s_trig1
// 6: V2 = 0.05*s_len2 + 0.5*s_trig2
// loss = focal + (P + min(V1,V2)) / nv
// Counter (int) lives at ws + NACC*NBLK floats; memset to 0 each call.
#define NACC 7

__device__ __forceinline__ float sl1f(float d) {
    float ad = fabsf(d);
    return ad < 1.0f ? 0.5f * d * d : ad - 0.5f;
}

// Round-9: single fused launch. Rounds 1-8 established the main body is
// pinned at 55-63 us regardless of structure (platform request/clock floor);
// the remaining cost was the second 1-block launch (~20-30 us of the bench
// tail). Last-finishing block performs the cross-block reduction in-place:
// store partials -> __threadfence (device scope, XCD-safe per G16) ->
// atomicAdd counter -> last block re-fences and reduces 7x1920 partials.
__global__ __launch_bounds__(256) void loss_fused(
    const float* __restrict__ re, const float* __restrict__ gt,
    float* __restrict__ ws, int* __restrict__ counter,
    float* __restrict__ out)
{
    const int tid = blockIdx.x * 256 + threadIdx.x;
    const int p = tid * 4;
    const int b = p / HW_;
    const int s = p - b * HW_;
    const float* rp = re + (size_t)b * CHW_ + s;
    const float* gp = gt + (size_t)b * CHW_ + s;

    // 20 coalesced dwordx4 streams (round-2 shape: best measured main body).
    float4 R[10], G[10];
#pragma unroll
    for (int c = 0; c < 10; ++c) {
        R[c] = *(const float4*)(rp + c * HW_);
        G[c] = *(const float4*)(gp + c * HW_);
    }

    float acc[NACC];
#pragma unroll
    for (int i = 0; i < NACC; ++i) acc[i] = 0.0f;

#pragma unroll
    for (int j = 0; j < 4; ++j) {
        #define RC(c) (((const float*)&R[c])[j])
        #define GC(c) (((const float*)&G[c])[j])
        const float g = GC(0), r = RC(0);
        const float m = (g == 1.0f) ? 1.0f : 0.0f;
        acc[0] += m;
        const float pos = (g >= 0.1f) ? 1.0f : 0.0f;
        const float neg = ((g >= 0.0f) && (g < 0.1f)) ? 1.0f : 0.0f;
        acc[1] += pos;
        const float safe = fminf(fmaxf(r, 1e-6f), 1.0f - 1e-6f);
        const float d0 = g - r;
        acc[2] += pos * (d0 * d0) * logf(safe + 6e-8f);
        const float omg = 1.0f - g;
        const float omg2 = omg * omg;
        acc[3] += neg * (r * r) * logf(1.0f + 6e-8f - safe) * (omg2 * omg2);

        const float r1 = RC(1), r2 = RC(2), r3 = RC(3), r4v = RC(4);
        const float r5 = RC(5), r6 = RC(6), r7 = RC(7), r8 = RC(8), r9 = RC(9);
        const float g1 = GC(1), g2 = GC(2), g3 = GC(3), g4v = GC(4);
        const float g5 = GC(5), g6 = GC(6), g7 = GC(7), g8 = GC(8), g9 = GC(9);

        // P: 0.5*pos_ch + 0.5*const + 0.1*height
        const float sp = sl1f(r1 - g1) + sl1f(r2 - g2);
        const float c1 = 1.0f - r5 * r5 - r4v * r4v;
        const float c2 = 1.0f - r8 * r8 - r7 * r7;
        const float sc = c1 * c1 + c2 * c2;
        const float sh = sl1f(r9 - g9);
        acc[4] += m * (0.5f * sp + 0.5f * sc + 0.1f * sh);

        // V1: 0.05*len1 + 0.5*trig1
        const float d44 = r4v - g4v, d77 = r7 - g7;
        const float d55 = r5 - g5,  d88 = r8 - g8;
        const float t1 = d44 * d44 + d77 * d77 + d55 * d55 + d88 * d88;
        const float l1 = sl1f(r3 - g3) + sl1f(r6 - g6);
        acc[5] += m * (0.05f * l1 + 0.5f * t1);

        // V2: 0.05*len2 + 0.5*trig2
        const float d47 = r4v - g7, d74 = r7 - g4v;
        const float d58 = r5 - g8,  d85 = r8 - g5;
        const float t2 = d47 * d47 + d74 * d74 + d58 * d58 + d85 * d85;
        const float l2 = sl1f(r3 - g6) + sl1f(r6 - g3);
        acc[6] += m * (0.05f * l2 + 0.5f * t2);
        #undef RC
        #undef GC
    }

    // block reduction: wave shuffle (64 lanes) -> LDS (4 waves) -> store
    __shared__ float smem[NACC][4];
#pragma unroll
    for (int i = 0; i < NACC; ++i) {
        float v = acc[i];
#pragma unroll
        for (int off = 32; off > 0; off >>= 1) v += __shfl_down(v, off, 64);
        if ((threadIdx.x & 63) == 0) smem[i][threadIdx.x >> 6] = v;
    }
    __syncthreads();
    if (threadIdx.x < NACC) {
        const int i = threadIdx.x;
        ws[i * NBLK + blockIdx.x] =
            smem[i][0] + smem[i][1] + smem[i][2] + smem[i][3];
    }
    __syncthreads();   // partial stores issued before the fence below

    // ---- last-block-done cross-block reduction ----
    __shared__ int is_last;
    if (threadIdx.x == 0) {
        __threadfence();                       // release: partials visible
        const int old = atomicAdd(counter, 1); // device-scope
        is_last = (old == NBLK - 1) ? 1 : 0;
    }
    __syncthreads();
    if (!is_last) return;

    __threadfence();                           // acquire: see all partials

    float racc[NACC];
#pragma unroll
    for (int i = 0; i < NACC; ++i) racc[i] = 0.0f;
    for (int idx = threadIdx.x; idx < NBLK; idx += 256) {
#pragma unroll
        for (int i = 0; i < NACC; ++i)
            racc[i] += ws[i * NBLK + idx];
    }

    __syncthreads();   // smem reuse: all waves past first-phase reads
#pragma unroll
    for (int i = 0; i < NACC; ++i) {
        float v = racc[i];
#pragma unroll
        for (int off = 32; off > 0; off >>= 1) v += __shfl_down(v, off, 64);
        if ((threadIdx.x & 63) == 0) smem[i][threadIdx.x >> 6] = v;
    }
    __syncthreads();

    if (threadIdx.x == 0) {
        float slot[NACC];
#pragma unroll
        for (int i = 0; i < NACC; ++i)
            slot[i] = smem[i][0] + smem[i][1] + smem[i][2] + smem[i][3];
        const float nv    = slot[0];
        const float npos  = slot[1];
        const float pterm = -slot[2];
        const float nterm = -slot[3];
        const float focal = (npos == 0.0f) ? nterm : (pterm + nterm) / npos;
        out[0] = focal + (slot[4] + fminf(slot[5], slot[6])) / nv;
    }
}

extern "C" void kernel_launch(void* const* d_in, const int* in_sizes, int n_in,
                              void* d_out, int out_size, void* d_ws, size_t ws_size,
                              hipStream_t stream)
{
    const float* re = (const float*)d_in[0];
    const float* gt = (const float*)d_in[1];
    float* ws   = (float*)d_ws;
    int* counter = (int*)((float*)d_ws + NACC * NBLK);
    float* out  = (float*)d_out;

    // counter is poisoned 0xAA each call -> zero it (async, capture-safe).
    hipMemsetAsync(counter, 0, sizeof(int), stream);
    loss_fused<<<NBLK, 256, 0, stream>>>(re, gt, ws, counter, out);
}